// Round 14
// baseline (47.233 us; speedup 1.0000x reference)
//
#include <hip/hip_runtime.h>
#include <hip/hip_bf16.h>

typedef __bf16 bf16x8 __attribute__((ext_vector_type(8)));
typedef float  f32x4  __attribute__((ext_vector_type(4)));

#define UBV   35.0f
#define SUMC  150.0f

__device__ __forceinline__ float lrelu(float x) { return fmaxf(x, 0.2f * x); }

__device__ __forceinline__ unsigned pk8(float a, float b) {
    return ((unsigned)__builtin_amdgcn_cvt_pk_fp8_f32(a, b, 0, false)) & 0xffffu;
}
__device__ __forceinline__ long mk64(unsigned lo, unsigned hi) {
    return (long)(((unsigned long long)hi << 32) | (unsigned long long)lo);
}
__device__ __forceinline__ void async16(void* lds_uniform, const void* gsrc) {
    __builtin_amdgcn_global_load_lds(
        (__attribute__((address_space(1))) void*)(gsrc),
        (__attribute__((address_space(3))) void*)(lds_uniform),
        16, 0, 0);
}

// ---------------------------------------------------------------------------
// sigma mapping prep: byte-identical since R4 (absmax 0.125).
// ---------------------------------------------------------------------------

__global__ void prep_kernel(const float* __restrict__ W1, const float* __restrict__ b1,
                            const float* __restrict__ W2, const float* __restrict__ b2,
                            const float* __restrict__ W3, const float* __restrict__ b3,
                            __bf16* __restrict__ w1p, uint2* __restrict__ w2p,
                            uint2* __restrict__ w3c)
{
    int idx = blockIdx.x * blockDim.x + threadIdx.x;
    if (idx < 1664) {
        int lane = idx & 63;
        int nt = idx >> 6;
        int c16 = lane & 15, g = lane >> 4;
        int kk = nt >> 1, hh = nt & 1;
        int kap = kk * 32 + (c16 >> 2) * 8 + hh * 4 + (c16 & 3);
        bf16x8 v;
        #pragma unroll
        for (int j = 0; j < 8; ++j) {
            int k = g * 8 + j;
            float x = 0.f;
            if (kap < 400) {
                if (k < 17) x = W1[kap * 17 + k];
                else if (k == 17) x = b1[kap];
            } else if (kap == 400) {
                if (k == 17) x = 1.0f;
            }
            v[j] = (__bf16)x;
        }
        *(bf16x8*)(w1p + idx * 8) = v;
    } else if (idx < 1664 + 16640) {
        int i2 = idx - 1664;
        int fg = i2 >> 6, lane = i2 & 63;
        int q = fg / 65, rem = fg % 65;
        int t = rem / 13, kt = rem % 13;
        int c16 = lane & 15, g = lane >> 4;
        int local = t * 16 + c16;
        int ff = q * 79 + local;
        float v[8];
        #pragma unroll
        for (int j = 0; j < 8; ++j) {
            int kap = kt * 32 + g * 8 + j;
            float x = 0.f;
            if (local == 79) {
                x = (kap == 400) ? 1.0f : 0.f;
            } else if (local < 79 && ff < 300) {
                if (kap < 400) x = W2[ff * 400 + kap];
                else if (kap == 400) x = b2[ff];
            }
            v[j] = x;
        }
        uint2 d;
        d.x = pk8(v[0], v[1]) | (pk8(v[2], v[3]) << 16);
        d.y = pk8(v[4], v[5]) | (pk8(v[6], v[7]) << 16);
        w2p[i2] = d;
    } else if (idx < 1664 + 16640 + 768) {
        int i3 = idx - 1664 - 16640;
        int fg = i3 >> 6, lane = i3 & 63;
        int q = fg / 3, k2 = fg % 3;
        int o = lane & 15, g = lane >> 4;
        float v[8];
        #pragma unroll
        for (int j = 0; j < 8; ++j) {
            int t2  = 2 * k2 + (j >> 2);
            int rho = g * 4 + (j & 3);
            int local = t2 * 16 + rho;
            float x = 0.f;
            if (o < 5 && t2 < 5) {
                if (local == 79) x = b3[o] * 0.25f;
                else if (local < 79 && q * 79 + local < 300)
                    x = W3[o * 300 + q * 79 + local];
            }
            v[j] = x;
        }
        uint2 d;
        d.x = pk8(v[0], v[1]) | (pk8(v[2], v[3]) << 16);
        d.y = pk8(v[4], v[5]) | (pk8(v[6], v[7]) << 16);
        w3c[i3] = d;
    }
}

// ---------------------------------------------------------------------------
// R14 DIAGNOSTIC: R13's exact structure, REPS=2 idempotent -> actor ~65us
// rises above the ~39us harness fills -> first counters for a streaming
// (non-resident-W2) build. Pre-committed: WRITE~2.6MB => no spill (then
// MfmaUtil/VALUBusy/Occupancy decide stall-vs-compute); WRITE>=40MB =>
// streaming build still spills; MfmaUtil*dur >> 6us => MFMA model wrong.
// ---------------------------------------------------------------------------
#define REPS 2

__global__ __launch_bounds__(256, 1)
void actor_kernel(const float* __restrict__ state,
                  const __bf16* __restrict__ w1p,
                  const uint2* __restrict__ w2p,
                  const uint2* __restrict__ w3c,
                  float* __restrict__ out)
{
    __shared__ __align__(16) char s_mem[2][33792];   // 67,584B double buffer

    const int tid = threadIdx.x;
    const int wid = tid >> 6;            // wave -> m-tile pair
    const int ln  = tid & 63;
    const int g   = ln >> 4, c16 = ln & 15;
    const int brow = blockIdx.x << 7;    // 128 rows/block

    #pragma unroll 1
    for (int rep = 0; rep < REPS; ++rep) {
        int zz = rep;
        asm volatile("" : "+v"(zz));
        const int z0 = zz >> 20;         // always 0 at runtime; defeats LICM

        // ---- stage W1p -> buf0 AND quarter q0 -> buf1 ----
        {
            const char* gb1 = (const char*)w1p + z0;
            #pragma unroll
            for (int i = wid; i < 26; i += 4)
                async16(&s_mem[0][0] + i * 1024, gb1 + i * 1024 + ln * 16);
            const char* gb2 = (const char*)w2p + z0;   // quarter 0
            #pragma unroll
            for (int i = wid; i < 33; i += 4)
                async16(&s_mem[1][0] + i * 1024, gb2 + i * 1024 + ln * 16);
        }

        // ---- state A-frags for both m-tiles ----
        bf16x8 sbA, sbB;
        {
            const float* spA = state + (brow + wid * 32 + c16) * 17 + z0;
            const float* spB = spA + 16 * 17;
            if (g == 0) {
                #pragma unroll
                for (int j = 0; j < 8; ++j) { sbA[j] = (__bf16)spA[j]; sbB[j] = (__bf16)spB[j]; }
            } else if (g == 1) {
                #pragma unroll
                for (int j = 0; j < 8; ++j) { sbA[j] = (__bf16)spA[8 + j]; sbB[j] = (__bf16)spB[8 + j]; }
            } else if (g == 2) {
                sbA[0] = (__bf16)spA[16]; sbB[0] = (__bf16)spB[16];
                sbA[1] = (__bf16)1.0f;    sbB[1] = (__bf16)1.0f;
                #pragma unroll
                for (int j = 2; j < 8; ++j) { sbA[j] = (__bf16)0.f; sbB[j] = (__bf16)0.f; }
            } else {
                #pragma unroll
                for (int j = 0; j < 8; ++j) { sbA[j] = (__bf16)0.f; sbB[j] = (__bf16)0.f; }
            }
        }

        __syncthreads();   // W1 (buf0) and q0 (buf1) staged

        // ---- Phase A: h1 for both m-tiles; frvA/frvB in registers ----
        long frvA[13], frvB[13];
        #pragma unroll
        for (int kt = 0; kt < 13; ++kt) {
            bf16x8 we = *(const bf16x8*)(&s_mem[0][0] + ((2 * kt) * 64 + ln) * 16);
            bf16x8 wo = *(const bf16x8*)(&s_mem[0][0] + ((2 * kt + 1) * 64 + ln) * 16);
            f32x4 aeA = {0.f,0.f,0.f,0.f}, aoA = {0.f,0.f,0.f,0.f};
            f32x4 aeB = {0.f,0.f,0.f,0.f}, aoB = {0.f,0.f,0.f,0.f};
            aeA = __builtin_amdgcn_mfma_f32_16x16x32_bf16(we, sbA, aeA, 0, 0, 0);
            aoA = __builtin_amdgcn_mfma_f32_16x16x32_bf16(wo, sbA, aoA, 0, 0, 0);
            aeB = __builtin_amdgcn_mfma_f32_16x16x32_bf16(we, sbB, aeB, 0, 0, 0);
            aoB = __builtin_amdgcn_mfma_f32_16x16x32_bf16(wo, sbB, aoB, 0, 0, 0);
            frvA[kt] = mk64(
                pk8(lrelu(aeA[0]), lrelu(aeA[1])) | (pk8(lrelu(aeA[2]), lrelu(aeA[3])) << 16),
                pk8(lrelu(aoA[0]), lrelu(aoA[1])) | (pk8(lrelu(aoA[2]), lrelu(aoA[3])) << 16));
            frvB[kt] = mk64(
                pk8(lrelu(aeB[0]), lrelu(aeB[1])) | (pk8(lrelu(aeB[2]), lrelu(aeB[3])) << 16),
                pk8(lrelu(aoB[0]), lrelu(aoB[1])) | (pk8(lrelu(aoB[2]), lrelu(aoB[3])) << 16));
        }

        __syncthreads();   // buf0 free for q1

        // ---- q-loop: consume buf[(q&1)^1]; stage q+1 into buf[q&1] ----
        f32x4 ccsA = {0.f, 0.f, 0.f, 0.f};
        f32x4 ccsB = {0.f, 0.f, 0.f, 0.f};
        const long* gw3 = (const long*)w3c + z0;

        #pragma unroll 1
        for (int q = 0; q < 4; ++q) {
            if (q < 3) {
                char* lb = &s_mem[q & 1][0];
                const char* gb = (const char*)w2p + (q + 1) * 33280 + z0;
                #pragma unroll
                for (int i = wid; i < 33; i += 4)
                    async16(lb + i * 1024, gb + i * 1024 + ln * 16);
            }
            long w3q0 = gw3[(q * 3 + 0) * 64 + ln];
            long w3q1 = gw3[(q * 3 + 1) * 64 + ln];
            long w3q2 = gw3[(q * 3 + 2) * 64 + ln];

            const long* wq = (const long*)(&s_mem[(q & 1) ^ 1][0]);
            f32x4 aA0 = {0.f,0.f,0.f,0.f}, aA1 = {0.f,0.f,0.f,0.f}, aA2 = {0.f,0.f,0.f,0.f};
            f32x4 aA3 = {0.f,0.f,0.f,0.f}, aA4 = {0.f,0.f,0.f,0.f};
            f32x4 aB0 = {0.f,0.f,0.f,0.f}, aB1 = {0.f,0.f,0.f,0.f}, aB2 = {0.f,0.f,0.f,0.f};
            f32x4 aB3 = {0.f,0.f,0.f,0.f}, aB4 = {0.f,0.f,0.f,0.f};
            #pragma unroll
            for (int kt = 0; kt < 13; ++kt) {
                long f0 = wq[(0 * 13 + kt) * 64 + ln];
                long f1 = wq[(1 * 13 + kt) * 64 + ln];
                long f2 = wq[(2 * 13 + kt) * 64 + ln];
                long f3 = wq[(3 * 13 + kt) * 64 + ln];
                long f4 = wq[(4 * 13 + kt) * 64 + ln];
                aA0 = __builtin_amdgcn_mfma_f32_16x16x32_fp8_fp8(f0, frvA[kt], aA0, 0, 0, 0);
                aB0 = __builtin_amdgcn_mfma_f32_16x16x32_fp8_fp8(f0, frvB[kt], aB0, 0, 0, 0);
                aA1 = __builtin_amdgcn_mfma_f32_16x16x32_fp8_fp8(f1, frvA[kt], aA1, 0, 0, 0);
                aB1 = __builtin_amdgcn_mfma_f32_16x16x32_fp8_fp8(f1, frvB[kt], aB1, 0, 0, 0);
                aA2 = __builtin_amdgcn_mfma_f32_16x16x32_fp8_fp8(f2, frvA[kt], aA2, 0, 0, 0);
                aB2 = __builtin_amdgcn_mfma_f32_16x16x32_fp8_fp8(f2, frvB[kt], aB2, 0, 0, 0);
                aA3 = __builtin_amdgcn_mfma_f32_16x16x32_fp8_fp8(f3, frvA[kt], aA3, 0, 0, 0);
                aB3 = __builtin_amdgcn_mfma_f32_16x16x32_fp8_fp8(f3, frvB[kt], aB3, 0, 0, 0);
                aA4 = __builtin_amdgcn_mfma_f32_16x16x32_fp8_fp8(f4, frvA[kt], aA4, 0, 0, 0);
                aB4 = __builtin_amdgcn_mfma_f32_16x16x32_fp8_fp8(f4, frvB[kt], aB4, 0, 0, 0);
            }
            {
                unsigned d0 = pk8(lrelu(aA0[0]), lrelu(aA0[1])) | (pk8(lrelu(aA0[2]), lrelu(aA0[3])) << 16);
                unsigned d1 = pk8(lrelu(aA1[0]), lrelu(aA1[1])) | (pk8(lrelu(aA1[2]), lrelu(aA1[3])) << 16);
                unsigned d2 = pk8(lrelu(aA2[0]), lrelu(aA2[1])) | (pk8(lrelu(aA2[2]), lrelu(aA2[3])) << 16);
                unsigned d3 = pk8(lrelu(aA3[0]), lrelu(aA3[1])) | (pk8(lrelu(aA3[2]), lrelu(aA3[3])) << 16);
                unsigned d4 = pk8(lrelu(aA4[0]), lrelu(aA4[1])) | (pk8(lrelu(aA4[2]), lrelu(aA4[3])) << 16);
                f32x4 cc = {0.f, 0.f, 0.f, 0.f};
                cc = __builtin_amdgcn_mfma_f32_16x16x32_fp8_fp8(w3q0, mk64(d0, d1), cc, 0, 0, 0);
                cc = __builtin_amdgcn_mfma_f32_16x16x32_fp8_fp8(w3q1, mk64(d2, d3), cc, 0, 0, 0);
                cc = __builtin_amdgcn_mfma_f32_16x16x32_fp8_fp8(w3q2, mk64(d4, 0u),  cc, 0, 0, 0);
                ccsA += cc;
            }
            {
                unsigned d0 = pk8(lrelu(aB0[0]), lrelu(aB0[1])) | (pk8(lrelu(aB0[2]), lrelu(aB0[3])) << 16);
                unsigned d1 = pk8(lrelu(aB1[0]), lrelu(aB1[1])) | (pk8(lrelu(aB1[2]), lrelu(aB1[3])) << 16);
                unsigned d2 = pk8(lrelu(aB2[0]), lrelu(aB2[1])) | (pk8(lrelu(aB2[2]), lrelu(aB2[3])) << 16);
                unsigned d3 = pk8(lrelu(aB3[0]), lrelu(aB3[1])) | (pk8(lrelu(aB3[2]), lrelu(aB3[3])) << 16);
                unsigned d4 = pk8(lrelu(aB4[0]), lrelu(aB4[1])) | (pk8(lrelu(aB4[2]), lrelu(aB4[3])) << 16);
                f32x4 cc = {0.f, 0.f, 0.f, 0.f};
                cc = __builtin_amdgcn_mfma_f32_16x16x32_fp8_fp8(w3q0, mk64(d0, d1), cc, 0, 0, 0);
                cc = __builtin_amdgcn_mfma_f32_16x16x32_fp8_fp8(w3q1, mk64(d2, d3), cc, 0, 0, 0);
                cc = __builtin_amdgcn_mfma_f32_16x16x32_fp8_fp8(w3q2, mk64(d4, 0u),  cc, 0, 0, 0);
                ccsB += cc;
            }
            if (q < 3) __syncthreads();
        }

        // ---- Epilogue: 32 lanes/wave solve QP for 32 rows ----
        float tA4 = __shfl_xor(ccsA[0], 16);
        float sB0 = __shfl_xor(ccsB[0], 16);
        float sB1 = __shfl_xor(ccsB[1], 16);
        float sB2 = __shfl_xor(ccsB[2], 16);
        float sB3 = __shfl_xor(ccsB[3], 16);

        if (ln < 32) {
            float v[5];
            if (ln < 16) {
                v[0] = -lrelu(ccsA[0]); v[1] = -lrelu(ccsA[1]);
                v[2] = -lrelu(ccsA[2]); v[3] = -lrelu(ccsA[3]);
                v[4] = -lrelu(tA4);
            } else {
                v[0] = -lrelu(sB0); v[1] = -lrelu(sB1);
                v[2] = -lrelu(sB2); v[3] = -lrelu(sB3);
                v[4] = -lrelu(ccsB[0]);
            }

            float bp[10];
            #pragma unroll
            for (int i = 0; i < 5; ++i) { bp[i] = v[i]; bp[i + 5] = v[i] - UBV; }
            float blo = -1e30f, glo = 0.f;
            #pragma unroll
            for (int j = 0; j < 10; ++j) {
                float b = bp[j];
                float gsum = 0.f;
                #pragma unroll
                for (int i = 0; i < 5; ++i) {
                    float zc = v[i] - b;
                    zc = fminf(fmaxf(zc, 0.f), UBV);
                    gsum += zc;
                }
                if (gsum >= SUMC && b > blo) { blo = b; glo = gsum; }
            }
            float bhi = 1e30f;
            #pragma unroll
            for (int j = 0; j < 10; ++j) {
                float b = bp[j];
                if (b > blo && b < bhi) bhi = b;
            }
            float mid = 0.5f * (blo + bhi);
            int nfree = 0;
            #pragma unroll
            for (int i = 0; i < 5; ++i)
                nfree += (v[i] > mid && v[i] < mid + UBV) ? 1 : 0;
            float nu = (nfree > 0) ? blo + (glo - SUMC) / (float)nfree : blo;

            int row = brow + wid * 32 + ln;
            #pragma unroll
            for (int o = 0; o < 5; ++o) {
                float zf = v[o] - nu;
                zf = fminf(fmaxf(zf, 0.f), UBV);
                out[row * 5 + o] = zf;
            }
        }

        __syncthreads();   // q3 buffer drained by all waves before restage
    }
}

extern "C" void kernel_launch(void* const* d_in, const int* in_sizes, int n_in,
                              void* d_out, int out_size, void* d_ws, size_t ws_size,
                              hipStream_t stream) {
    const float* state = (const float*)d_in[0];
    const float* W1    = (const float*)d_in[1];
    const float* b1    = (const float*)d_in[2];
    const float* W2    = (const float*)d_in[3];
    const float* b2    = (const float*)d_in[4];
    const float* W3    = (const float*)d_in[5];
    const float* b3    = (const float*)d_in[6];
    float* out = (float*)d_out;

    char* base = (char*)d_ws;
    __bf16* w1p = (__bf16*)base;                   // 26,624B
    uint2*  w2p = (uint2*)(base + 26624);          // 133,120B
    uint2*  w3c = (uint2*)(base + 26624 + 133120); // 6,144B

    const int total = 1664 + 16640 + 768;
    prep_kernel<<<(total + 255) / 256, 256, 0, stream>>>(W1, b1, W2, b2, W3, b3,
                                                         w1p, w2p, w3c);

    int B = in_sizes[0] / 17;                      // 65536
    actor_kernel<<<B / 128, 256, 0, stream>>>(state, w1p, w2p, w3c, out);
}

// Round 15
// 28.592 us; speedup vs baseline: 1.6520x; 1.6520x over previous
//
#include <hip/hip_runtime.h>
#include <hip/hip_bf16.h>

typedef __bf16 bf16x8 __attribute__((ext_vector_type(8)));
typedef float  f32x4  __attribute__((ext_vector_type(4)));
typedef long   long2v __attribute__((ext_vector_type(2)));

#define UBV   35.0f
#define SUMC  150.0f

__device__ __forceinline__ float lrelu(float x) { return fmaxf(x, 0.2f * x); }

// one 32-bit word of 4 fp8(e4m3): 2 cvt_pk ops, bit-identical to the old
// (pk8(a,b) | pk8(c,d)<<16) but without the and/shl/or chain.
__device__ __forceinline__ unsigned pkword(float a, float b, float c, float d) {
    unsigned w = (unsigned)__builtin_amdgcn_cvt_pk_fp8_f32(a, b, 0, false);  // low16
    w = (unsigned)__builtin_amdgcn_cvt_pk_fp8_f32(c, d, (int)w, true);       // high16, keeps low
    return w;
}
__device__ __forceinline__ long mk64(unsigned lo, unsigned hi) {
    return (long)(((unsigned long long)hi << 32) | (unsigned long long)lo);
}
__device__ __forceinline__ void async16(void* lds_uniform, const void* gsrc) {
    __builtin_amdgcn_global_load_lds(
        (__attribute__((address_space(1))) void*)(gsrc),
        (__attribute__((address_space(3))) void*)(lds_uniform),
        16, 0, 0);
}

// ---------------------------------------------------------------------------
// sigma mapping: see R4. Values identical since R4 (absmax 0.125).
// R15 change: w2p reordered for paired-kt b128 reads. Per (q,t) 6656B block:
//   kt<12: uint2 idx = (kt>>1)*128 + lane*2 + (kt&1)   (pairs share a 16B unit)
//   kt=12: uint2 idx = 768 + lane
// ---------------------------------------------------------------------------

__global__ void prep_kernel(const float* __restrict__ W1, const float* __restrict__ b1,
                            const float* __restrict__ W2, const float* __restrict__ b2,
                            const float* __restrict__ W3, const float* __restrict__ b3,
                            __bf16* __restrict__ w1p, uint2* __restrict__ w2p,
                            uint2* __restrict__ w3c)
{
    int idx = blockIdx.x * blockDim.x + threadIdx.x;
    if (idx < 1664) {
        int lane = idx & 63;
        int nt = idx >> 6;
        int c16 = lane & 15, g = lane >> 4;
        int kk = nt >> 1, hh = nt & 1;
        int kap = kk * 32 + (c16 >> 2) * 8 + hh * 4 + (c16 & 3);
        bf16x8 v;
        #pragma unroll
        for (int j = 0; j < 8; ++j) {
            int k = g * 8 + j;
            float x = 0.f;
            if (kap < 400) {
                if (k < 17) x = W1[kap * 17 + k];
                else if (k == 17) x = b1[kap];
            } else if (kap == 400) {
                if (k == 17) x = 1.0f;
            }
            v[j] = (__bf16)x;
        }
        *(bf16x8*)(w1p + idx * 8) = v;
    } else if (idx < 1664 + 16640) {
        int i2 = idx - 1664;
        int fg = i2 >> 6, lane = i2 & 63;
        int q = fg / 65, rem = fg % 65;
        int t = rem / 13, kt = rem % 13;
        int c16 = lane & 15, g = lane >> 4;
        int local = t * 16 + c16;
        int ff = q * 79 + local;
        float v[8];
        #pragma unroll
        for (int j = 0; j < 8; ++j) {
            int kap = kt * 32 + g * 8 + j;
            float x = 0.f;
            if (local == 79) {
                x = (kap == 400) ? 1.0f : 0.f;
            } else if (local < 79 && ff < 300) {
                if (kap < 400) x = W2[ff * 400 + kap];
                else if (kap == 400) x = b2[ff];
            }
            v[j] = x;
        }
        uint2 d;
        d.x = pkword(v[0], v[1], v[2], v[3]);
        d.y = pkword(v[4], v[5], v[6], v[7]);
        int within = (kt < 12) ? ((kt >> 1) * 128 + lane * 2 + (kt & 1))
                               : (768 + lane);
        w2p[(q * 5 + t) * 832 + within] = d;
    } else if (idx < 1664 + 16640 + 768) {
        int i3 = idx - 1664 - 16640;
        int fg = i3 >> 6, lane = i3 & 63;
        int q = fg / 3, k2 = fg % 3;
        int o = lane & 15, g = lane >> 4;
        float v[8];
        #pragma unroll
        for (int j = 0; j < 8; ++j) {
            int t2  = 2 * k2 + (j >> 2);
            int rho = g * 4 + (j & 3);
            int local = t2 * 16 + rho;
            float x = 0.f;
            if (o < 5 && t2 < 5) {
                if (local == 79) x = b3[o] * 0.25f;
                else if (local < 79 && q * 79 + local < 300)
                    x = W3[o * 300 + q * 79 + local];
            }
            v[j] = x;
        }
        uint2 d;
        d.x = pkword(v[0], v[1], v[2], v[3]);
        d.y = pkword(v[4], v[5], v[6], v[7]);
        w3c[i3] = d;
    }
}

// ---------------------------------------------------------------------------
// Actor R15: R13 geometry (512 x 256thr, 4 waves, dual m-tile/wave, double-
// buffered quarters) with the phase-B loop restructured t-outer/kt-inner:
// pack(t) [VALU] overlaps MFMA(t+1) -- R14 counters showed MFMA (33%) and
// VALU (47%) pipes running SEQUENTIALLY (sum ~ dur). Paired-kt b128 reads
// (65->35 LDS reads/q), pkword (2-op fp8 word), w3 frags hoisted. Per-acc
// MFMA order unchanged -> bit-identical results (absmax 0.125).
// ---------------------------------------------------------------------------
__global__ __launch_bounds__(256, 1)
void actor_kernel(const float* __restrict__ state,
                  const __bf16* __restrict__ w1p,
                  const uint2* __restrict__ w2p,
                  const uint2* __restrict__ w3c,
                  float* __restrict__ out)
{
    __shared__ __align__(16) char s_mem[2][33792];   // 67,584B double buffer

    const int tid = threadIdx.x;
    const int wid = tid >> 6;            // wave -> m-tile pair
    const int ln  = tid & 63;
    const int g   = ln >> 4, c16 = ln & 15;
    const int brow = blockIdx.x << 7;    // 128 rows/block

    // ---- stage W1p -> buf0 AND quarter q0 -> buf1 (both in flight) ----
    {
        const char* gb1 = (const char*)w1p;
        #pragma unroll
        for (int i = wid; i < 26; i += 4)
            async16(&s_mem[0][0] + i * 1024, gb1 + i * 1024 + ln * 16);
        const char* gb2 = (const char*)w2p;   // quarter 0
        #pragma unroll
        for (int i = wid; i < 33; i += 4)     // 512B overread, stays in ws
            async16(&s_mem[1][0] + i * 1024, gb2 + i * 1024 + ln * 16);
    }

    // ---- state A-frags for both m-tiles ----
    bf16x8 sbA, sbB;
    {
        const float* spA = state + (brow + wid * 32 + c16) * 17;
        const float* spB = spA + 16 * 17;
        if (g == 0) {
            #pragma unroll
            for (int j = 0; j < 8; ++j) { sbA[j] = (__bf16)spA[j]; sbB[j] = (__bf16)spB[j]; }
        } else if (g == 1) {
            #pragma unroll
            for (int j = 0; j < 8; ++j) { sbA[j] = (__bf16)spA[8 + j]; sbB[j] = (__bf16)spB[8 + j]; }
        } else if (g == 2) {
            sbA[0] = (__bf16)spA[16]; sbB[0] = (__bf16)spB[16];
            sbA[1] = (__bf16)1.0f;    sbB[1] = (__bf16)1.0f;   // bias carrier k=17
            #pragma unroll
            for (int j = 2; j < 8; ++j) { sbA[j] = (__bf16)0.f; sbB[j] = (__bf16)0.f; }
        } else {
            #pragma unroll
            for (int j = 0; j < 8; ++j) { sbA[j] = (__bf16)0.f; sbB[j] = (__bf16)0.f; }
        }
    }

    // ---- hoisted W3 fragment loads (12 longs, 24 VGPR, L2-hot) ----
    long w3r[4][3];
    {
        const long* gw3 = (const long*)w3c;
        #pragma unroll
        for (int q = 0; q < 4; ++q)
            #pragma unroll
            for (int k2 = 0; k2 < 3; ++k2)
                w3r[q][k2] = gw3[(q * 3 + k2) * 64 + ln];
    }

    __syncthreads();   // W1 (buf0) and q0 (buf1) staged

    // ---- Phase A: h1 for both m-tiles; frvA/frvB stay in registers ----
    long frvA[13], frvB[13];
    #pragma unroll
    for (int kt = 0; kt < 13; ++kt) {
        bf16x8 we = *(const bf16x8*)(&s_mem[0][0] + ((2 * kt) * 64 + ln) * 16);
        bf16x8 wo = *(const bf16x8*)(&s_mem[0][0] + ((2 * kt + 1) * 64 + ln) * 16);
        f32x4 aeA = {0.f,0.f,0.f,0.f}, aoA = {0.f,0.f,0.f,0.f};
        f32x4 aeB = {0.f,0.f,0.f,0.f}, aoB = {0.f,0.f,0.f,0.f};
        aeA = __builtin_amdgcn_mfma_f32_16x16x32_bf16(we, sbA, aeA, 0, 0, 0);
        aoA = __builtin_amdgcn_mfma_f32_16x16x32_bf16(wo, sbA, aoA, 0, 0, 0);
        aeB = __builtin_amdgcn_mfma_f32_16x16x32_bf16(we, sbB, aeB, 0, 0, 0);
        aoB = __builtin_amdgcn_mfma_f32_16x16x32_bf16(wo, sbB, aoB, 0, 0, 0);
        frvA[kt] = mk64(
            pkword(lrelu(aeA[0]), lrelu(aeA[1]), lrelu(aeA[2]), lrelu(aeA[3])),
            pkword(lrelu(aoA[0]), lrelu(aoA[1]), lrelu(aoA[2]), lrelu(aoA[3])));
        frvB[kt] = mk64(
            pkword(lrelu(aeB[0]), lrelu(aeB[1]), lrelu(aeB[2]), lrelu(aeB[3])),
            pkword(lrelu(aoB[0]), lrelu(aoB[1]), lrelu(aoB[2]), lrelu(aoB[3])));
    }

    __syncthreads();   // buf0 free for q1

    // ---- q-loop: consume buf[(q&1)^1] t-by-t; stage q+1 into buf[q&1] ----
    f32x4 ccsA = {0.f, 0.f, 0.f, 0.f};
    f32x4 ccsB = {0.f, 0.f, 0.f, 0.f};

    #pragma unroll 1
    for (int q = 0; q < 4; ++q) {
        if (q < 3) {
            char* lb = &s_mem[q & 1][0];
            const char* gb = (const char*)w2p + (q + 1) * 33280;
            #pragma unroll
            for (int i = wid; i < 33; i += 4)
                async16(lb + i * 1024, gb + i * 1024 + ln * 16);
        }

        const char* bufp = &s_mem[(q & 1) ^ 1][0];
        unsigned wdA[5], wdB[5];
        #pragma unroll
        for (int t = 0; t < 5; ++t) {
            const char* bt = bufp + t * 6656;
            f32x4 aA = {0.f,0.f,0.f,0.f}, aB = {0.f,0.f,0.f,0.f};
            #pragma unroll
            for (int kt2 = 0; kt2 < 6; ++kt2) {
                long2v p = *(const long2v*)(bt + kt2 * 1024 + ln * 16);
                aA = __builtin_amdgcn_mfma_f32_16x16x32_fp8_fp8(p[0], frvA[2 * kt2],     aA, 0, 0, 0);
                aB = __builtin_amdgcn_mfma_f32_16x16x32_fp8_fp8(p[0], frvB[2 * kt2],     aB, 0, 0, 0);
                aA = __builtin_amdgcn_mfma_f32_16x16x32_fp8_fp8(p[1], frvA[2 * kt2 + 1], aA, 0, 0, 0);
                aB = __builtin_amdgcn_mfma_f32_16x16x32_fp8_fp8(p[1], frvB[2 * kt2 + 1], aB, 0, 0, 0);
            }
            long p12 = *(const long*)(bt + 6144 + ln * 8);
            aA = __builtin_amdgcn_mfma_f32_16x16x32_fp8_fp8(p12, frvA[12], aA, 0, 0, 0);
            aB = __builtin_amdgcn_mfma_f32_16x16x32_fp8_fp8(p12, frvB[12], aB, 0, 0, 0);
            // pack(t) overlaps MFMA(t+1): independent chains
            wdA[t] = pkword(lrelu(aA[0]), lrelu(aA[1]), lrelu(aA[2]), lrelu(aA[3]));
            wdB[t] = pkword(lrelu(aB[0]), lrelu(aB[1]), lrelu(aB[2]), lrelu(aB[3]));
        }
        {
            f32x4 cc = {0.f, 0.f, 0.f, 0.f};
            cc = __builtin_amdgcn_mfma_f32_16x16x32_fp8_fp8(w3r[q][0], mk64(wdA[0], wdA[1]), cc, 0, 0, 0);
            cc = __builtin_amdgcn_mfma_f32_16x16x32_fp8_fp8(w3r[q][1], mk64(wdA[2], wdA[3]), cc, 0, 0, 0);
            cc = __builtin_amdgcn_mfma_f32_16x16x32_fp8_fp8(w3r[q][2], mk64(wdA[4], 0u),     cc, 0, 0, 0);
            ccsA += cc;
        }
        {
            f32x4 cc = {0.f, 0.f, 0.f, 0.f};
            cc = __builtin_amdgcn_mfma_f32_16x16x32_fp8_fp8(w3r[q][0], mk64(wdB[0], wdB[1]), cc, 0, 0, 0);
            cc = __builtin_amdgcn_mfma_f32_16x16x32_fp8_fp8(w3r[q][1], mk64(wdB[2], wdB[3]), cc, 0, 0, 0);
            cc = __builtin_amdgcn_mfma_f32_16x16x32_fp8_fp8(w3r[q][2], mk64(wdB[4], 0u),     cc, 0, 0, 0);
            ccsB += cc;
        }
        if (q < 3) __syncthreads();   // q+1 staged AND current buffer free
    }

    // ---- Epilogue: 32 lanes/wave solve QP for 32 rows ----
    float tA4 = __shfl_xor(ccsA[0], 16);
    float sB0 = __shfl_xor(ccsB[0], 16);
    float sB1 = __shfl_xor(ccsB[1], 16);
    float sB2 = __shfl_xor(ccsB[2], 16);
    float sB3 = __shfl_xor(ccsB[3], 16);

    if (ln < 32) {
        float v[5];
        if (ln < 16) {
            v[0] = -lrelu(ccsA[0]); v[1] = -lrelu(ccsA[1]);
            v[2] = -lrelu(ccsA[2]); v[3] = -lrelu(ccsA[3]);
            v[4] = -lrelu(tA4);
        } else {
            v[0] = -lrelu(sB0); v[1] = -lrelu(sB1);
            v[2] = -lrelu(sB2); v[3] = -lrelu(sB3);
            v[4] = -lrelu(ccsB[0]);
        }

        float bp[10];
        #pragma unroll
        for (int i = 0; i < 5; ++i) { bp[i] = v[i]; bp[i + 5] = v[i] - UBV; }
        float blo = -1e30f, glo = 0.f;
        #pragma unroll
        for (int j = 0; j < 10; ++j) {
            float b = bp[j];
            float gsum = 0.f;
            #pragma unroll
            for (int i = 0; i < 5; ++i) {
                float zc = v[i] - b;
                zc = fminf(fmaxf(zc, 0.f), UBV);
                gsum += zc;
            }
            if (gsum >= SUMC && b > blo) { blo = b; glo = gsum; }
        }
        float bhi = 1e30f;
        #pragma unroll
        for (int j = 0; j < 10; ++j) {
            float b = bp[j];
            if (b > blo && b < bhi) bhi = b;
        }
        float mid = 0.5f * (blo + bhi);
        int nfree = 0;
        #pragma unroll
        for (int i = 0; i < 5; ++i)
            nfree += (v[i] > mid && v[i] < mid + UBV) ? 1 : 0;
        float nu = (nfree > 0) ? blo + (glo - SUMC) / (float)nfree : blo;

        int row = brow + wid * 32 + ln;
        #pragma unroll
        for (int o = 0; o < 5; ++o) {
            float zf = v[o] - nu;
            zf = fminf(fmaxf(zf, 0.f), UBV);
            out[row * 5 + o] = zf;
        }
    }
}

extern "C" void kernel_launch(void* const* d_in, const int* in_sizes, int n_in,
                              void* d_out, int out_size, void* d_ws, size_t ws_size,
                              hipStream_t stream) {
    const float* state = (const float*)d_in[0];
    const float* W1    = (const float*)d_in[1];
    const float* b1    = (const float*)d_in[2];
    const float* W2    = (const float*)d_in[3];
    const float* b2    = (const float*)d_in[4];
    const float* W3    = (const float*)d_in[5];
    const float* b3    = (const float*)d_in[6];
    float* out = (float*)d_out;

    char* base = (char*)d_ws;
    __bf16* w1p = (__bf16*)base;                   // 26,624B
    uint2*  w2p = (uint2*)(base + 26624);          // 133,120B
    uint2*  w3c = (uint2*)(base + 26624 + 133120); // 6,144B

    const int total = 1664 + 16640 + 768;
    prep_kernel<<<(total + 255) / 256, 256, 0, stream>>>(W1, b1, W2, b2, W3, b3,
                                                         w1p, w2p, w3c);

    int B = in_sizes[0] / 17;                      // 65536
    actor_kernel<<<B / 128, 256, 0, stream>>>(state, w1p, w2p, w3c, out);
}